// Round 3
// baseline (129.500 us; speedup 1.0000x reference)
//
#include <hip/hip_runtime.h>
#include <math.h>

// Problem constants (setup_inputs: data (16,256,1024) f32)
#define B_   16
#define V_   256
#define R_   1024
#define HR_  20      // G[1]+T[1] = 4+16
#define HV_  10      // G[0]+T[0] = 2+8
#define KTOP 8       // OS_N - K_ORDER = 32-24
#define CAN  16      // 2*T[0]

// ---------------- Stage 1: OS-CFAR along R ----------------
// One block = 256 consecutive r of one (b,v) row. LDS halo tile, then
// branch-free top-8 selection (insertion compare-swap chain) per thread.
// Window offsets relative to CUT r: {-20..-5} U {+5..+20}  (32 samples).
__global__ __launch_bounds__(256) void os_kernel(const float* __restrict__ data,
                                                 float* __restrict__ os,
                                                 float alpha) {
    const int tiles_per_row = R_ / 256;                 // 4
    const int row = blockIdx.x / tiles_per_row;         // b*V + v
    const int r0  = (blockIdx.x % tiles_per_row) * 256;
    const float* __restrict__ src = data + (size_t)row * R_;

    __shared__ float lds[256 + 2 * HR_];                // 296 floats
    for (int i = threadIdx.x; i < 256 + 2 * HR_; i += 256) {
        int idx = (r0 - HR_ + i) & (R_ - 1);            // circular pad
        lds[i] = src[idx];
    }
    __syncthreads();

    const int t = threadIdx.x;
    float top[KTOP];
#pragma unroll
    for (int i = 0; i < KTOP; ++i) top[i] = -1e30f;

    // lds offsets: {0..15} U {25..40} (lds[t] == src[r-20])
#pragma unroll
    for (int j = 0; j < 32; ++j) {
        const int off = (j < 16) ? j : j + 9;           // 16..31 -> 25..40
        float v = lds[t + off];
#pragma unroll
        for (int i = 0; i < KTOP; ++i) {
            float mx = fmaxf(top[i], v);
            v = fminf(top[i], v);
            top[i] = mx;
        }
    }
    os[(size_t)row * R_ + r0 + t] = alpha * top[KTOP - 1];
}

// ---------------- Stage 2: CA along V ----------------
// out[b][v][r] = mean over dv in {-10..-3} U {+3..+10} of os[b][(v+dv)%V][r]
__global__ __launch_bounds__(256) void ca_kernel(const float* __restrict__ os,
                                                 float* __restrict__ out) {
    const int gid = blockIdx.x * 256 + threadIdx.x;     // b*V*R + v*R + r
    const int r  = gid & (R_ - 1);
    const int bv = gid >> 10;
    const int v  = bv & (V_ - 1);
    const int b  = bv >> 8;
    const float* __restrict__ base = os + (size_t)b * V_ * R_;

    float s = 0.f;
#pragma unroll
    for (int j = 0; j < 8; ++j) {                       // dv = -10..-3
        int vv = (v + (j - HV_) + V_) & (V_ - 1);
        s += base[(size_t)vv * R_ + r];
    }
#pragma unroll
    for (int j = 0; j < 8; ++j) {                       // dv = +3..+10
        int vv = (v + (j + 3)) & (V_ - 1);
        s += base[(size_t)vv * R_ + r];
    }
    out[gid] = s * (1.0f / CAN);
}

// ---------------- Host: replicate reference alpha solve (float64) ----------------
static double lf_(double n) {
    n = n + 1.0;
    if (n < 9.0) {
        double f = 1.0;
        for (int i = 2; i <= (int)(n + 0.5); ++i) f *= (double)i;
        return log(f);
    }
    return 0.5 * (log(2.0 * M_PI) - log(n)) +
           n * (log(n + 1.0 / (12.0 * n - 0.1 / n)) - 1.0);
}

static double fun_(double k, double n, double t, double pfa) {
    double s = 0.0;
    for (int i = 0; i < (int)k; ++i) s += log(n - (double)i + t);
    return lf_(n) - lf_(n - k) - s - log(pfa);
}

// Faithful replication of the reference's false-position bracket update.
static double solve_alpha_t_ref(void) {
    const double k = 24.0, n = 32.0, pfa = 1e-5;
    double t_max = 1e32, t_min = 1.0, m_n = 1.0;
    for (int it = 0; it < 10000; ++it) {
        double fmax_ = fun_(k, n, t_max, pfa);
        double fmin_ = fun_(k, n, t_min, pfa);
        m_n = t_max - fmax_ * (t_min - t_max) / (fmin_ - fmax_);
        double fm = fun_(k, n, m_n, pfa);
        if (fm == 0.0 || fabs(t_max - t_min) < 1e-4) return m_n;
        if (fmax_ * fm < 0.0)      t_min = m_n;   // ref: if fun(t_max)*f_m_n < 0: t_min = m_n
        else if (fmin_ * fm < 0.0) t_max = m_n;   // ref: elif fun(t_min)*f_m_n < 0: t_max = m_n
        else break;
    }
    return m_n;
}

extern "C" void kernel_launch(void* const* d_in, const int* in_sizes, int n_in,
                              void* d_out, int out_size, void* d_ws, size_t ws_size,
                              hipStream_t stream) {
    const float* data = (const float*)d_in[0];
    float* out = (float*)d_out;
    float* os  = (float*)d_ws;                    // needs 16*256*1024*4 = 16.78 MB

    const float alpha = (float)sqrt(solve_alpha_t_ref());

    const int blocks1 = B_ * V_ * (R_ / 256);     // 16384
    os_kernel<<<blocks1, 256, 0, stream>>>(data, os, alpha);

    const int blocks2 = (B_ * V_ * R_) / 256;     // 16384
    ca_kernel<<<blocks2, 256, 0, stream>>>(os, out);
}

// Round 4
// 102.308 us; speedup vs baseline: 1.2658x; 1.2658x over previous
//
#include <hip/hip_runtime.h>
#include <math.h>

// Problem constants (setup_inputs: data (16,256,1024) f32)
#define B_   16
#define V_   256
#define R_   1024
#define HR_  20      // G[1]+T[1] = 4+16
#define HV_  10      // G[0]+T[0] = 2+8
#define KTOP 8       // OS_N - K_ORDER = 32-24
#define CAN  16      // 2*T[0]

// Compare-exchange, descending (a=max, b=min)
__device__ __forceinline__ void ce(float& a, float& b) {
    float mx = fmaxf(a, b);
    float mn = fminf(a, b);
    a = mx; b = mn;
}

// Batcher odd-even mergesort, 8 elems, descending, 19 CE
__device__ __forceinline__ void sort8(float* c) {
    ce(c[0],c[1]); ce(c[2],c[3]); ce(c[4],c[5]); ce(c[6],c[7]);
    ce(c[0],c[2]); ce(c[1],c[3]); ce(c[1],c[2]);
    ce(c[4],c[6]); ce(c[5],c[7]); ce(c[5],c[6]);
    ce(c[0],c[4]); ce(c[2],c[6]); ce(c[2],c[4]);
    ce(c[1],c[5]); ce(c[3],c[7]); ce(c[3],c[5]);
    ce(c[1],c[2]); ce(c[3],c[4]); ce(c[5],c[6]);
}

// a,b sorted descending. m = top-8 multiset of a∪b (bitonic), then sort it
// descending with a 12-CE bitonic cleaner.
__device__ __forceinline__ void merge_top8_sorted(const float* a, const float* b, float* m) {
#pragma unroll
    for (int i = 0; i < 8; ++i) m[i] = fmaxf(a[i], b[7 - i]);
    ce(m[0],m[4]); ce(m[1],m[5]); ce(m[2],m[6]); ce(m[3],m[7]);
    ce(m[0],m[2]); ce(m[1],m[3]); ce(m[4],m[6]); ce(m[5],m[7]);
    ce(m[0],m[1]); ce(m[2],m[3]); ce(m[4],m[5]); ce(m[6],m[7]);
}

// ---------------- Stage 1: OS-CFAR along R ----------------
// One block per (b,v) row (1024 r). Each thread computes 4 consecutive r.
// Window rel. to r: {-20..-5} U {+5..+20}. lds[i] = src[(i-20) mod 1024],
// so element r reads lds[r..r+15] and lds[r+25..r+40].
__global__ __launch_bounds__(256) void os_kernel(const float* __restrict__ data,
                                                 float* __restrict__ os,
                                                 float alpha) {
    const int row = blockIdx.x;                         // b*V + v
    const float* __restrict__ src = data + (size_t)row * R_;

    __shared__ float lds[R_ + 2 * HR_ + 4];             // 1064 floats
    for (int i = threadIdx.x; i < R_ + 2 * HR_ + 4; i += 256)
        lds[i] = src[(i - HR_) & (R_ - 1)];             // circular
    __syncthreads();

    const int q = threadIdx.x * 4;                      // first r of this thread
    // Left span lds[q .. q+19], right span lds[q+24 .. q+43] — 10 aligned b128 loads.
    float L[20], Rr[20];
#pragma unroll
    for (int j = 0; j < 5; ++j)
        *(float4*)&L[4 * j] = *(const float4*)&lds[q + 4 * j];
#pragma unroll
    for (int j = 0; j < 5; ++j)
        *(float4*)&Rr[4 * j] = *(const float4*)&lds[q + 24 + 4 * j];

    float res[4];
#pragma unroll
    for (int e = 0; e < 4; ++e) {
        // 32 window samples: L[e..e+15], Rr[e+1..e+16]
        float c0[8], c1[8], c2[8], c3[8];
#pragma unroll
        for (int j = 0; j < 8; ++j) {
            c0[j] = L[e + j];
            c1[j] = L[e + 8 + j];
            c2[j] = Rr[e + 1 + j];
            c3[j] = Rr[e + 9 + j];
        }
        sort8(c0); sort8(c1); sort8(c2); sort8(c3);
        float m01[8], m23[8];
        merge_top8_sorted(c0, c1, m01);
        merge_top8_sorted(c2, c3, m23);
        // top-8 of all 32 (multiset), then its min = 8th largest
        float f0 = fmaxf(m01[0], m23[7]);
        float f1 = fmaxf(m01[1], m23[6]);
        float f2 = fmaxf(m01[2], m23[5]);
        float f3 = fmaxf(m01[3], m23[4]);
        float f4 = fmaxf(m01[4], m23[3]);
        float f5 = fmaxf(m01[5], m23[2]);
        float f6 = fmaxf(m01[6], m23[1]);
        float f7 = fmaxf(m01[7], m23[0]);
        float mn = fminf(fminf(fminf(f0, f1), fminf(f2, f3)),
                         fminf(fminf(f4, f5), fminf(f6, f7)));
        res[e] = alpha * mn;
    }
    *(float4*)&os[(size_t)row * R_ + q] = *(float4*)res;
}

// ---------------- Stage 2: CA along V (running window sums) ----------------
// out[v] = (W21 - W5)/16 where W21 = sum os[v-10..v+10], W5 = sum os[v-2..v+2].
#define VT 32    // v-outputs per thread
__global__ __launch_bounds__(256) void ca_kernel(const float* __restrict__ os,
                                                 float* __restrict__ out) {
    const int rblk = blockIdx.x & (R_ / 256 - 1);                   // 0..3
    const int vblk = (blockIdx.x >> 2) & (V_ / VT - 1);             // 0..7
    const int b    = blockIdx.x >> 5;
    const int r    = rblk * 256 + threadIdx.x;
    const int v0   = vblk * VT;
    const float* __restrict__ base = os + (size_t)b * V_ * R_ + r;
    float* __restrict__ o = out + (size_t)b * V_ * R_ + r;

    float W21 = 0.f, W5 = 0.f;
#pragma unroll
    for (int d = -10; d <= 10; ++d) W21 += base[((v0 + d) & (V_ - 1)) * R_];
#pragma unroll
    for (int d = -2; d <= 2; ++d)   W5  += base[((v0 + d) & (V_ - 1)) * R_];

#pragma unroll 4
    for (int v = v0; v < v0 + VT; ++v) {
        o[v * R_] = (W21 - W5) * (1.0f / CAN);
        W21 += base[((v + 11) & (V_ - 1)) * R_] - base[((v - 10) & (V_ - 1)) * R_];
        W5  += base[((v + 3 ) & (V_ - 1)) * R_] - base[((v - 2 ) & (V_ - 1)) * R_];
    }
}

// ---------------- Host: replicate reference alpha solve (float64) ----------------
static double lf_(double n) {
    n = n + 1.0;
    if (n < 9.0) {
        double f = 1.0;
        for (int i = 2; i <= (int)(n + 0.5); ++i) f *= (double)i;
        return log(f);
    }
    return 0.5 * (log(2.0 * M_PI) - log(n)) +
           n * (log(n + 1.0 / (12.0 * n - 0.1 / n)) - 1.0);
}

static double fun_(double k, double n, double t, double pfa) {
    double s = 0.0;
    for (int i = 0; i < (int)k; ++i) s += log(n - (double)i + t);
    return lf_(n) - lf_(n - k) - s - log(pfa);
}

static double solve_alpha_t_ref(void) {
    const double k = 24.0, n = 32.0, pfa = 1e-5;
    double t_max = 1e32, t_min = 1.0, m_n = 1.0;
    for (int it = 0; it < 10000; ++it) {
        double fmax_ = fun_(k, n, t_max, pfa);
        double fmin_ = fun_(k, n, t_min, pfa);
        m_n = t_max - fmax_ * (t_min - t_max) / (fmin_ - fmax_);
        double fm = fun_(k, n, m_n, pfa);
        if (fm == 0.0 || fabs(t_max - t_min) < 1e-4) return m_n;
        if (fmax_ * fm < 0.0)      t_min = m_n;
        else if (fmin_ * fm < 0.0) t_max = m_n;
        else break;
    }
    return m_n;
}

extern "C" void kernel_launch(void* const* d_in, const int* in_sizes, int n_in,
                              void* d_out, int out_size, void* d_ws, size_t ws_size,
                              hipStream_t stream) {
    const float* data = (const float*)d_in[0];
    float* out = (float*)d_out;
    float* os  = (float*)d_ws;                    // 16*256*1024*4 = 16.78 MB

    const float alpha = (float)sqrt(solve_alpha_t_ref());

    os_kernel<<<B_ * V_, 256, 0, stream>>>(data, os, alpha);

    const int blocks2 = B_ * (R_ / 256) * (V_ / VT);   // 16*4*8 = 512
    ca_kernel<<<blocks2, 256, 0, stream>>>(os, out);
}